// Round 8
// baseline (495.469 us; speedup 1.0000x reference)
//
#include <hip/hip_runtime.h>
#include <hip/hip_bf16.h>

// QKVAttention: L2-distance attention. B=8, T=4096, C=192, fp32 in/out.
// out[b,t,:] = sum_s exp(-||q_t-k_s||*192^-0.5) v_s / sum_s exp(...)
// exp arg bounded in [-3,0] -> no online softmax needed.
//
// R12: occupancy test AT THE LOW-DS WORKING POINT. Evidence: R0(dbuf,8w/CU)=
// R10(singlebuf,16w/CU)=R11(2-qa half-DS,8w/CU)=157-162us -> neither barrier
// structure nor DS throughput nor (high-DS) occupancy is the limiter alone;
// no pipe >63% in R11. Remaining cell: more waves at LOW DS/unit. R11's grid
// 512 = exactly 2 blocks/CU; here s-split=4 -> grid 1024 -> 3 blocks/CU
// (43008B LDS x3 = 129KB) = 12 waves/CU = 3 waves/SIMD.
//  - attnh core = R11 verbatim (passed, absmax 2.44e-4): 4 waves x 32 q-rows
//    (two 16-row Q fragments), 12 K + 12 V LDS reads feed 48 MFMAs/iter,
//    K,V single-buffered, 2 barriers/iter.
//  - sh in 0..3, 32 s-iters of 32 tokens each; 4 partials atomicAdd'ed into
//    out (commutative f32; rounding-order variance ~1e-6 << 1e-3 threshold).
//  - blockIdx&7 = batch -> XCD (proven 256-thr mapping: FETCH 18.6MB).
//  - prep / combine: proven structure; combine sums 4 lparts.

#define BB 8
#define TT 4096
#define CD 192
#define NSH 4     // s-split

typedef __attribute__((ext_vector_type(8))) short short8;   // 8 bf16 (4 VGPR)
typedef __attribute__((ext_vector_type(4))) float float4v;  // MFMA C/D
typedef __attribute__((ext_vector_type(2))) unsigned int uint2v;

// (log2 e)^2 / 192  : p = exp2(-sqrt(max(q2A+k2A-2*A2C*dot, 0)))
constexpr float A2C = (float)(2.0813689810056077 / 192.0);

static __device__ __forceinline__ unsigned short f2bf(float f) {
  unsigned u = __builtin_bit_cast(unsigned, f);
  unsigned r = u + 0x7fffu + ((u >> 16) & 1u);   // RNE (inputs finite)
  return (unsigned short)(r >> 16);
}
static __device__ __forceinline__ float bf2f(unsigned short b) {
  return __builtin_bit_cast(float, (unsigned)b << 16);
}

// ---------------- fused prepass: qkv -> qsw/ksw/vsw fragments + q2/k2 -------
// Also zeroes `out` (atomic accumulation target for attnh).
// block = (b, sc): 32 tokens x 576 ch. Coalesced float4 read -> bf16 LDS tile,
// then emit MFMA-fragment units (64 lanes x 16B each) + A2C-prescaled rounded
// row sumsq. No atomics here: each block owns its 32 tokens' q2/k2 entries.
__global__ __launch_bounds__(256) void prep(
    const float* __restrict__ qkv, short8* __restrict__ qsw,
    short8* __restrict__ ksw, short8* __restrict__ vsw,
    float* __restrict__ q2, float* __restrict__ k2,
    float* __restrict__ out) {
  // zero out: 8*4096*192 floats = 1572864 float4 over 1024 blk x 256 thr
  {
    float4v* o4 = (float4v*)out;
    int base = blockIdx.x * 256 + threadIdx.x;
#pragma unroll
    for (int j = 0; j < 6; ++j)
      o4[base + j * 262144] = (float4v){0.f, 0.f, 0.f, 0.f};
  }

  __shared__ unsigned short tile[32 * 584];   // row stride 584 (1168B, 16-mult)
  const int t = threadIdx.x;
  const int b = blockIdx.x >> 7;
  const int sc = blockIdx.x & 127;
  const float* src = qkv + ((size_t)(b * TT + sc * 32)) * (3 * CD);
#pragma unroll
  for (int j = 0; j < 18; ++j) {              // 4608 float4s / 256 thr
    int f = j * 256 + t;
    int row = f / 144, c4 = (f % 144) * 4;
    float4v x = *(const float4v*)(src + (size_t)row * 576 + c4);
    unsigned r0 = (unsigned)f2bf(x[0]) | ((unsigned)f2bf(x[1]) << 16);
    unsigned r1 = (unsigned)f2bf(x[2]) | ((unsigned)f2bf(x[3]) << 16);
    *(uint2v*)&tile[row * 584 + c4] = (uint2v){r0, r1};
  }
  __syncthreads();

  const int lane = t & 63, w = t >> 6;
  const int L = lane & 15, q = lane >> 4;
  // waves 0,1 -> q (s16o = w), waves 2,3 -> k (s16o = w-2)
  const int which = w >> 1;
  const int s16o = w & 1;
  const int row = s16o * 16 + L;
  short8* dst = which ? ksw : qsw;
  const size_t ubase = ((size_t)(b * 256 + sc * 2 + s16o)) * 6;
  float ss = 0.f;
#pragma unroll
  for (int ch = 0; ch < 6; ++ch) {
    short8 fr = *(const short8*)&tile[row * 584 + which * CD + ch * 32 + q * 8];
#pragma unroll
    for (int j = 0; j < 8; ++j) {
      float f = bf2f((unsigned short)fr[j]);
      ss += f * f;
    }
    dst[(ubase + ch) * 64 + lane] = fr;
  }
  ss += __shfl_xor(ss, 16);
  ss += __shfl_xor(ss, 32);                   // sum over 4 quads (192 ch)
  if (lane < 16)
    (which ? k2 : q2)[b * TT + sc * 32 + s16o * 16 + lane] = ss * A2C;

  // v fragments: 12 nt2-units, 3 per wave. lane(q,L): V[q*8+j][nt2*16+L]
#pragma unroll
  for (int i = 0; i < 3; ++i) {
    int nt2 = w * 3 + i;
    short8 fr;
#pragma unroll
    for (int j = 0; j < 8; ++j)
      fr[j] = (short)tile[(q * 8 + j) * 584 + 2 * CD + nt2 * 16 + L];
    vsw[((size_t)(b * 12 + nt2) * 128 + sc) * 64 + lane] = fr;
  }
}

// ---------------- main fused attention (one s-quarter per block) ------------
// grid 1024 = 8 b x 32 q-tiles(128 rows) x 4 s-quarters; block 256 = 4 waves
// x 32 q-rows (two 16-row fragments each). 32 s-iters of 32; K and V
// single-buffered via global_load_lds w=16 (12 units each, 3/wave).
// 43008B LDS -> 3 blocks/CU = 12 waves/CU = 3 waves/SIMD.
__global__ __launch_bounds__(256, 3) void attnh(
    const short8* __restrict__ qsw, const short8* __restrict__ ksw,
    const short8* __restrict__ vsw, const float* __restrict__ q2,
    const float* __restrict__ k2, float* __restrict__ out,
    float* __restrict__ lpart) {
  // LDS: K 12KB | V 12KB | P scratch 4 waves x 32x36 fp32 (18432B)
  __shared__ __align__(16) unsigned char s_lds[24576 + 18432];
  float* ldsP = (float*)(s_lds + 24576);

  const int tid = threadIdx.x;
  const int w = tid >> 6;
  const int lane = tid & 63;
  const int L = lane & 15;
  const int q = lane >> 4;
  const int b = blockIdx.x & 7;      // batch -> XCD (all blocks of batch b on
  const int qt = (blockIdx.x >> 3) & 31;   //   one XCD -> K/V L2-resident)
  const int sh = blockIdx.x >> 8;    // s-quarter 0..3
  const int q0 = qt * 128 + w * 32;  // this wave's 32 q-rows
  const size_t bT = (size_t)b * TT;
  const int it0 = sh * 32;           // first 32-token tile of this quarter

  float* pw = ldsP + w * 1152;       // wave-private 32x36 P scratch

  auto stageK = [&](int itile) {
    const char* gk = (const char*)(ksw + ((size_t)(b * 256 + 2 * itile)) * 6 * 64);
#pragma unroll
    for (int j = 0; j < 3; ++j) {
      int u = w * 3 + j;
      const char* ga = gk + (u * 64 + lane) * 16;
      char* la = (char*)s_lds + u * 1024;
      __builtin_amdgcn_global_load_lds(
          (const __attribute__((address_space(1))) void*)ga,
          (__attribute__((address_space(3))) void*)la, 16, 0, 0);
    }
  };
  auto stageV = [&](int itile) {
#pragma unroll
    for (int j = 0; j < 3; ++j) {
      int u = w * 3 + j;
      const char* ga = (const char*)vsw +
                       (((size_t)(b * 12 + u) * 128 + itile) * 64 + lane) * 16;
      char* la = (char*)s_lds + 12288 + u * 1024;
      __builtin_amdgcn_global_load_lds(
          (const __attribute__((address_space(1))) void*)ga,
          (__attribute__((address_space(3))) void*)la, 16, 0, 0);
    }
  };

  // Q fragments for both 16-row groups: s16 = q0/16 + qa = qt*8 + w*2 + qa
  short8 qf[2][6];
#pragma unroll
  for (int qa = 0; qa < 2; ++qa)
#pragma unroll
    for (int ch = 0; ch < 6; ++ch)
      qf[qa][ch] =
          qsw[((size_t)(b * 256 + (q0 >> 4) + qa) * 6 + ch) * 64 + lane];

  float q2l[2][4];
#pragma unroll
  for (int qa = 0; qa < 2; ++qa)
#pragma unroll
    for (int r = 0; r < 4; ++r)
      q2l[qa][r] = q2[bT + q0 + qa * 16 + 4 * q + r];

  float4v oacc[2][12];
#pragma unroll
  for (int qa = 0; qa < 2; ++qa)
#pragma unroll
    for (int nt = 0; nt < 12; ++nt)
      oacc[qa][nt] = (float4v){0.f, 0.f, 0.f, 0.f};
  float lsum[2][4] = {{0.f, 0.f, 0.f, 0.f}, {0.f, 0.f, 0.f, 0.f}};

  stageK(it0);
  stageV(it0);
  __syncthreads();   // vmcnt(0) drain -> K(0),V(0) ready

#pragma unroll 1
  for (int it = 0; it < 32; ++it) {
    const int gt = it0 + it;
    const int s0 = gt * 32;

    float k2l[2];
    k2l[0] = k2[bT + s0 + L];
    k2l[1] = k2[bT + s0 + 16 + L];

    // ---- S = Q.K^T: 12 K reads feed 24 MFMAs (2 q-groups) ----
    float4v sacc[2][2];
#pragma unroll
    for (int qa = 0; qa < 2; ++qa)
#pragma unroll
      for (int nt = 0; nt < 2; ++nt)
        sacc[qa][nt] = (float4v){0.f, 0.f, 0.f, 0.f};
#pragma unroll
    for (int ch = 0; ch < 6; ++ch) {
      short8 kf0 = *(const short8*)(s_lds + ch * 1024 + lane * 16);
      short8 kf1 = *(const short8*)(s_lds + (6 + ch) * 1024 + lane * 16);
      sacc[0][0] = __builtin_amdgcn_mfma_f32_16x16x32_bf16(qf[0][ch], kf0, sacc[0][0], 0, 0, 0);
      sacc[0][1] = __builtin_amdgcn_mfma_f32_16x16x32_bf16(qf[0][ch], kf1, sacc[0][1], 0, 0, 0);
      sacc[1][0] = __builtin_amdgcn_mfma_f32_16x16x32_bf16(qf[1][ch], kf0, sacc[1][0], 0, 0, 0);
      sacc[1][1] = __builtin_amdgcn_mfma_f32_16x16x32_bf16(qf[1][ch], kf1, sacc[1][1], 0, 0, 0);
    }

    __syncthreads();   // B1: all waves done reading kbuf; drains stageV(gt)
                       //     issued last iter (vbuf ready for PV below)
    if (it + 1 < 32) stageK(gt + 1);   // refill kbuf; in flight through P+PV

    // ---- P = exp(-dist); C-layout row=4q+r -> LDS scratch -> A-layout ----
#pragma unroll
    for (int qa = 0; qa < 2; ++qa)
#pragma unroll
      for (int nt = 0; nt < 2; ++nt)
#pragma unroll
        for (int r = 0; r < 4; ++r) {
          float dot = sacc[qa][nt][r];
          float tt = fmaf(-2.f * A2C, dot, q2l[qa][r] + k2l[nt]);  // scaled d2
          float y = fmaxf(tt, 0.f);
          float p = __builtin_amdgcn_exp2f(-__builtin_amdgcn_sqrtf(y));
          lsum[qa][r] += p;
          pw[(qa * 16 + 4 * q + r) * 36 + nt * 16 + L] = p;
        }
    short8 paf[2];
#pragma unroll
    for (int qa = 0; qa < 2; ++qa) {
      float4v p0 = *(const float4v*)(pw + (qa * 16 + L) * 36 + q * 8);
      float4v p1 = *(const float4v*)(pw + (qa * 16 + L) * 36 + q * 8 + 4);
#pragma unroll
      for (int j = 0; j < 4; ++j) {
        paf[qa][j] = (short)f2bf(p0[j]);
        paf[qa][j + 4] = (short)f2bf(p1[j]);
      }
    }

    // ---- O += P.V: 12 V reads feed 24 MFMAs ----
#pragma unroll
    for (int nt = 0; nt < 12; ++nt) {
      short8 vf = *(const short8*)(s_lds + 12288 + nt * 1024 + lane * 16);
      oacc[0][nt] = __builtin_amdgcn_mfma_f32_16x16x32_bf16(paf[0], vf, oacc[0][nt], 0, 0, 0);
      oacc[1][nt] = __builtin_amdgcn_mfma_f32_16x16x32_bf16(paf[1], vf, oacc[1][nt], 0, 0, 0);
    }

    __syncthreads();   // B2: all waves done reading vbuf; drains stageK(gt+1)
    if (it + 1 < 32) stageV(gt + 1);   // refill vbuf; drained at next B1
  }

  // ---- epilogue: partial row sums to lpart; partial O atomicAdd to out ----
#pragma unroll
  for (int qa = 0; qa < 2; ++qa) {
    float* op = out + (bT + q0 + qa * 16) * (size_t)CD;
#pragma unroll
    for (int r = 0; r < 4; ++r) {
      float ls = lsum[qa][r];
#pragma unroll
      for (int m = 1; m < 16; m <<= 1) ls += __shfl_xor(ls, m);
      if (L == 0)
        lpart[(size_t)sh * (BB * TT) + bT + q0 + qa * 16 + 4 * q + r] = ls;
#pragma unroll
      for (int nt = 0; nt < 12; ++nt)
        atomicAdd(&op[(size_t)(4 * q + r) * CD + nt * 16 + L], oacc[qa][nt][r]);
    }
  }
}

// ---------------- combine: out *= 1/(l0+l1+l2+l3), in place -----------------
__global__ __launch_bounds__(256) void combine(
    float* __restrict__ out, const float* __restrict__ lpart) {
  const int idx = blockIdx.x * 256 + threadIdx.x;   // 8*4096*48 float4s
  const int row = idx / 48;
  float ls = 0.f;
#pragma unroll
  for (int j = 0; j < NSH; ++j) ls += lpart[row + j * (BB * TT)];
  const float inv = 1.f / ls;
  float4v a = ((const float4v*)out)[idx];
#pragma unroll
  for (int j = 0; j < 4; ++j) a[j] *= inv;
  ((float4v*)out)[idx] = a;
}

extern "C" void kernel_launch(void* const* d_in, const int* in_sizes, int n_in,
                              void* d_out, int out_size, void* d_ws, size_t ws_size,
                              hipStream_t stream) {
  (void)in_sizes; (void)n_in; (void)out_size; (void)ws_size;
  const float* qkv = (const float*)d_in[0];
  float* out = (float*)d_out;

  // ws: 3 x 12.58MB fragments + 2 x 131KB sumsq + 524KB lpart = 38.5MB
  short8* qsw = (short8*)d_ws;                       // 8*256*6 units
  short8* ksw = qsw + (size_t)BB * 256 * 6 * 64;
  short8* vsw = ksw + (size_t)BB * 256 * 6 * 64;     // 8*12*128 units
  float* q2 = (float*)(vsw + (size_t)BB * 12 * 128 * 64);
  float* k2 = q2 + (size_t)BB * TT;
  float* lpart = k2 + (size_t)BB * TT;               // NSH x [B,T] row sums

  prep<<<BB * 128, 256, 0, stream>>>(qkv, qsw, ksw, vsw, q2, k2, out);
  attnh<<<BB * 32 * NSH, 256, 0, stream>>>(qsw, ksw, vsw, q2, k2, out, lpart);
  combine<<<BB * TT * 48 / 256, 256, 0, stream>>>(out, lpart);
}

// Round 9
// 250.635 us; speedup vs baseline: 1.9769x; 1.9769x over previous
//
#include <hip/hip_runtime.h>
#include <hip/hip_bf16.h>

// QKVAttention: L2-distance attention. B=8, T=4096, C=192, fp32 in/out.
// out[b,t,:] = sum_s exp(-||q_t-k_s||*192^-0.5) v_s / sum_s exp(...)
// exp arg bounded in [-3,0] -> no online softmax needed.
//
// R13 = R0 (proven best, 248.4us / attn2 157us / absmax 2.4e-4) + T5 setprio.
// Why revert: R4=R10=R11 (157-162us) showed occupancy, DS volume and barrier
// count are each null levers; s-split variants add ~22us of epilogue overhead
// for zero attnh gain; R12's locality collapse was register-file occupancy
// (96 AGPR oacc + 84 VGPR > 170 -> 2 waves/SIMD -> grid oversubscribed ->
// XCD L2 thrash, FETCH 596MB). R0's lockstep 2-phase structure is the wall
// (MFMA busy ~41us of 157; all pipes <40%); the one in-structure lever with
// within-probe attn evidence is s_setprio(1) around MFMA clusters (+4-7%),
// exploiting phase drift between the 2 independent blocks/CU.

#define BB 8
#define TT 4096
#define CD 192

typedef __attribute__((ext_vector_type(8))) short short8;   // 8 bf16 (4 VGPR)
typedef __attribute__((ext_vector_type(4))) float float4v;  // MFMA C/D
typedef __attribute__((ext_vector_type(2))) unsigned int uint2v;

// (log2 e)^2 / 192  : p = exp2(-sqrt(max(q2A+k2A-2*A2C*dot, 0)))
constexpr float A2C = (float)(2.0813689810056077 / 192.0);

static __device__ __forceinline__ unsigned short f2bf(float f) {
  unsigned u = __builtin_bit_cast(unsigned, f);
  unsigned r = u + 0x7fffu + ((u >> 16) & 1u);   // RNE (inputs finite)
  return (unsigned short)(r >> 16);
}
static __device__ __forceinline__ float bf2f(unsigned short b) {
  return __builtin_bit_cast(float, (unsigned)b << 16);
}

// ---------------- fused prepass: qkv -> qsw/ksw/vsw fragments + q2/k2 -------
// block = (b, sc): 32 tokens x 576 ch. Coalesced float4 read -> bf16 LDS tile,
// then emit MFMA-fragment units (64 lanes x 16B each) + A2C-prescaled rounded
// row sumsq. No atomics: each block owns its 32 tokens' q2/k2 entries.
__global__ __launch_bounds__(256) void prep(
    const float* __restrict__ qkv, short8* __restrict__ qsw,
    short8* __restrict__ ksw, short8* __restrict__ vsw,
    float* __restrict__ q2, float* __restrict__ k2) {
  __shared__ unsigned short tile[32 * 584];   // row stride 584 (1168B, 16-mult)
  const int t = threadIdx.x;
  const int b = blockIdx.x >> 7;
  const int sc = blockIdx.x & 127;
  const float* src = qkv + ((size_t)(b * TT + sc * 32)) * (3 * CD);
#pragma unroll
  for (int j = 0; j < 18; ++j) {              // 4608 float4s / 256 thr
    int f = j * 256 + t;
    int row = f / 144, c4 = (f % 144) * 4;
    float4v x = *(const float4v*)(src + (size_t)row * 576 + c4);
    unsigned r0 = (unsigned)f2bf(x[0]) | ((unsigned)f2bf(x[1]) << 16);
    unsigned r1 = (unsigned)f2bf(x[2]) | ((unsigned)f2bf(x[3]) << 16);
    *(uint2v*)&tile[row * 584 + c4] = (uint2v){r0, r1};
  }
  __syncthreads();

  const int lane = t & 63, w = t >> 6;
  const int L = lane & 15, q = lane >> 4;
  // waves 0,1 -> q (s16o = w), waves 2,3 -> k (s16o = w-2)
  const int which = w >> 1;
  const int s16o = w & 1;
  const int row = s16o * 16 + L;
  short8* dst = which ? ksw : qsw;
  const size_t ubase = ((size_t)(b * 256 + sc * 2 + s16o)) * 6;
  float ss = 0.f;
#pragma unroll
  for (int ch = 0; ch < 6; ++ch) {
    short8 fr = *(const short8*)&tile[row * 584 + which * CD + ch * 32 + q * 8];
#pragma unroll
    for (int j = 0; j < 8; ++j) {
      float f = bf2f((unsigned short)fr[j]);
      ss += f * f;
    }
    dst[(ubase + ch) * 64 + lane] = fr;
  }
  ss += __shfl_xor(ss, 16);
  ss += __shfl_xor(ss, 32);                   // sum over 4 quads (192 ch)
  if (lane < 16)
    (which ? k2 : q2)[b * TT + sc * 32 + s16o * 16 + lane] = ss * A2C;

  // v fragments: 12 nt2-units, 3 per wave. lane(q,L): V[q*8+j][nt2*16+L]
#pragma unroll
  for (int i = 0; i < 3; ++i) {
    int nt2 = w * 3 + i;
    short8 fr;
#pragma unroll
    for (int j = 0; j < 8; ++j)
      fr[j] = (short)tile[(q * 8 + j) * 584 + 2 * CD + nt2 * 16 + L];
    vsw[((size_t)(b * 12 + nt2) * 128 + sc) * 64 + lane] = fr;
  }
}

// ---------------- main fused attention --------------------------------------
// grid 512 = 8 b x 64 q-tiles; block 256 = 4 waves x 16 q-rows.
// 128 s-iters of 32; K,V LDS double-buffered via global_load_lds width 16.
// 58368B LDS -> 2 blocks/CU (independent barriers overlap each other's drain).
__global__ __launch_bounds__(256, 2) void attn2(
    const short8* __restrict__ qsw, const short8* __restrict__ ksw,
    const short8* __restrict__ vsw, const float* __restrict__ q2,
    const float* __restrict__ k2, float* __restrict__ out) {
  // LDS: K dbuf 2x12KB | V dbuf 2x12KB | P scratch 4 waves x 16x36 fp32
  __shared__ __align__(16) unsigned char s_lds[49152 + 9216];
  float* ldsP = (float*)(s_lds + 49152);

  const int tid = threadIdx.x;
  const int w = tid >> 6;
  const int lane = tid & 63;
  const int L = lane & 15;
  const int q = lane >> 4;
  const int b = blockIdx.x & 7;      // batch -> XCD (and blk, blk+256 same CU
  const int qt = blockIdx.x >> 3;    //   share batch -> shared K/V in L2)
  const int q0 = qt * 64 + w * 16;   // this wave's 16 q-rows
  const size_t bT = (size_t)b * TT;

  float* pw = ldsP + w * 576;        // wave-private 16x36 P scratch

  // stage tile 'itile' (32 s-tokens: 12 K units + 12 V units) into buf
  auto stage = [&](int itile, int buf) {
    const char* gk = (const char*)(ksw + ((size_t)(b * 256 + 2 * itile)) * 6 * 64);
#pragma unroll
    for (int j = 0; j < 3; ++j) {
      int u = w * 3 + j;
      const char* ga = gk + (u * 64 + lane) * 16;
      char* la = (char*)s_lds + buf * 12288 + u * 1024;
      __builtin_amdgcn_global_load_lds(
          (const __attribute__((address_space(1))) void*)ga,
          (__attribute__((address_space(3))) void*)la, 16, 0, 0);
    }
#pragma unroll
    for (int j = 0; j < 3; ++j) {
      int u = w * 3 + j;
      const char* ga = (const char*)vsw +
                       (((size_t)(b * 12 + u) * 128 + itile) * 64 + lane) * 16;
      char* la = (char*)s_lds + 24576 + buf * 12288 + u * 1024;
      __builtin_amdgcn_global_load_lds(
          (const __attribute__((address_space(1))) void*)ga,
          (__attribute__((address_space(3))) void*)la, 16, 0, 0);
    }
  };

  // Q fragments: unit ((b*256 + s16)*6 + ch), s16 = q0/16 = qt*4 + w
  short8 qf[6];
#pragma unroll
  for (int ch = 0; ch < 6; ++ch)
    qf[ch] = qsw[((size_t)(b * 256 + (q0 >> 4)) * 6 + ch) * 64 + lane];

  float q2l[4];
#pragma unroll
  for (int r = 0; r < 4; ++r) q2l[r] = q2[bT + q0 + 4 * q + r];

  float4v oacc[12];
#pragma unroll
  for (int nt = 0; nt < 12; ++nt) oacc[nt] = (float4v){0.f, 0.f, 0.f, 0.f};
  float lsum[4] = {0.f, 0.f, 0.f, 0.f};

  stage(0, 0);
  __syncthreads();   // drains vmcnt -> tile0 ready

#pragma unroll 1
  for (int it = 0; it < 128; ++it) {
    const int cur = it & 1;
    if (it + 1 < 128) stage(it + 1, cur ^ 1);   // overlap with compute
    const int s0 = it * 32;

    float k2l[2];
    k2l[0] = k2[bT + s0 + L];
    k2l[1] = k2[bT + s0 + 16 + L];

    // ---- S = Q.K^T from LDS K fragments (setprio: favor MFMA wave) ----
    float4v sacc[2];
    sacc[0] = (float4v){0.f, 0.f, 0.f, 0.f};
    sacc[1] = (float4v){0.f, 0.f, 0.f, 0.f};
    __builtin_amdgcn_s_setprio(1);
#pragma unroll
    for (int ch = 0; ch < 6; ++ch) {
      short8 kf0 = *(const short8*)(s_lds + cur * 12288 + ch * 1024 + lane * 16);
      short8 kf1 = *(const short8*)(s_lds + cur * 12288 + (6 + ch) * 1024 + lane * 16);
      sacc[0] = __builtin_amdgcn_mfma_f32_16x16x32_bf16(qf[ch], kf0, sacc[0], 0, 0, 0);
      sacc[1] = __builtin_amdgcn_mfma_f32_16x16x32_bf16(qf[ch], kf1, sacc[1], 0, 0, 0);
    }
    __builtin_amdgcn_s_setprio(0);

    // ---- V fragments from LDS (issue early; used after P) ----
    short8 vf[12];
#pragma unroll
    for (int nt = 0; nt < 12; ++nt)
      vf[nt] = *(const short8*)(s_lds + 24576 + cur * 12288 + nt * 1024 + lane * 16);

    // ---- P = exp(-dist); C-layout row=4q+r, col=nt*16+L -> LDS -> A-layout --
#pragma unroll
    for (int nt = 0; nt < 2; ++nt)
#pragma unroll
      for (int r = 0; r < 4; ++r) {
        float dot = sacc[nt][r];
        float tt = fmaf(-2.f * A2C, dot, q2l[r] + k2l[nt]);   // scaled d2
        float y = fmaxf(tt, 0.f);
        float p = __builtin_amdgcn_exp2f(-__builtin_amdgcn_sqrtf(y));
        lsum[r] += p;
        pw[(4 * q + r) * 36 + nt * 16 + L] = p;
      }
    float4v p0 = *(const float4v*)(pw + L * 36 + q * 8);
    float4v p1 = *(const float4v*)(pw + L * 36 + q * 8 + 4);
    short8 paf;
#pragma unroll
    for (int j = 0; j < 4; ++j) {
      paf[j] = (short)f2bf(p0[j]);
      paf[j + 4] = (short)f2bf(p1[j]);
    }

    // ---- O += P.V (setprio: favor MFMA wave) ----
    __builtin_amdgcn_s_setprio(1);
#pragma unroll
    for (int nt = 0; nt < 12; ++nt)
      oacc[nt] = __builtin_amdgcn_mfma_f32_16x16x32_bf16(paf, vf[nt], oacc[nt], 0, 0, 0);
    __builtin_amdgcn_s_setprio(0);

    __syncthreads();   // drain stage(it+1) + release buf[cur]
  }

  // ---- epilogue: normalize, write out (wave-private) ----
#pragma unroll
  for (int r = 0; r < 4; ++r) {
    float ls = lsum[r];
#pragma unroll
    for (int m = 1; m < 16; m <<= 1) ls += __shfl_xor(ls, m);
    float linv = 1.f / ls;
#pragma unroll
    for (int nt = 0; nt < 12; ++nt)
      out[(bT + q0 + 4 * q + r) * CD + nt * 16 + L] = oacc[nt][r] * linv;
  }
}

extern "C" void kernel_launch(void* const* d_in, const int* in_sizes, int n_in,
                              void* d_out, int out_size, void* d_ws, size_t ws_size,
                              hipStream_t stream) {
  (void)in_sizes; (void)n_in; (void)out_size; (void)ws_size;
  const float* qkv = (const float*)d_in[0];
  float* out = (float*)d_out;

  short8* qsw = (short8*)d_ws;                       // 8*256*6 units
  short8* ksw = qsw + (size_t)BB * 256 * 6 * 64;
  short8* vsw = ksw + (size_t)BB * 256 * 6 * 64;     // 8*12*128 units
  float* q2 = (float*)(vsw + (size_t)BB * 12 * 128 * 64);
  float* k2 = q2 + (size_t)BB * TT;

  prep<<<BB * 128, 256, 0, stream>>>(qkv, qsw, ksw, vsw, q2, k2);
  attn2<<<BB * 64, 256, 0, stream>>>(qsw, ksw, vsw, q2, k2, out);
}

// Round 10
// 243.241 us; speedup vs baseline: 2.0369x; 1.0304x over previous
//
#include <hip/hip_runtime.h>
#include <hip/hip_bf16.h>

// QKVAttention: L2-distance attention. B=8, T=4096, C=192, fp32 in/out.
// out[b,t,:] = sum_s exp(-||q_t-k_s||*192^-0.5) v_s / sum_s exp(...)
// exp arg bounded in [-3,0] -> no online softmax needed.
//
// R14 = R0 core (proven 157us attn2, absmax 2.44e-4) minus setprio (R13: T5
// null-to-negative in lockstep structure, 157->160-162) plus per-iter VALU
// trims. Rationale: R10/R11/R13 proved occupancy, DS volume, barrier count,
// and wave priority are ALL null levers; all pipes <40%; the conserved cost
// across every null config is per-score VALU/TRANS work + per-iter
// addressing. Changes (no structural/numerics risk):
//  1. P pack via v_cvt_pk_bf16_f32 (4 inst) replaces manual RNE f2bf x8
//     (24 VALU/iter). Same RNE rounding.
//  2. Staging addresses strength-reduced: 6 persistent per-wave pointers
//     += const stride (K +12288, V +1024) instead of per-iter remultiply.
//  3. k2 row-sumsq prefetched one iter ahead (2 scalar loads off the
//     P-phase critical path).

#define BB 8
#define TT 4096
#define CD 192

typedef __attribute__((ext_vector_type(8))) short short8;   // 8 bf16 (4 VGPR)
typedef __attribute__((ext_vector_type(4))) float float4v;  // MFMA C/D
typedef __attribute__((ext_vector_type(4))) unsigned uint4v;
typedef __attribute__((ext_vector_type(2))) unsigned int uint2v;

// (log2 e)^2 / 192  : p = exp2(-sqrt(max(q2A+k2A-2*A2C*dot, 0)))
constexpr float A2C = (float)(2.0813689810056077 / 192.0);

static __device__ __forceinline__ unsigned short f2bf(float f) {
  unsigned u = __builtin_bit_cast(unsigned, f);
  unsigned r = u + 0x7fffu + ((u >> 16) & 1u);   // RNE (inputs finite)
  return (unsigned short)(r >> 16);
}
static __device__ __forceinline__ float bf2f(unsigned short b) {
  return __builtin_bit_cast(float, (unsigned)b << 16);
}
static __device__ __forceinline__ unsigned cvtpk_bf16(float lo, float hi) {
  unsigned r;                  // D[15:0]=bf16(lo), D[31:16]=bf16(hi), RNE
  asm("v_cvt_pk_bf16_f32 %0, %1, %2" : "=v"(r) : "v"(lo), "v"(hi));
  return r;
}

// ---------------- fused prepass: qkv -> qsw/ksw/vsw fragments + q2/k2 -------
// block = (b, sc): 32 tokens x 576 ch. Coalesced float4 read -> bf16 LDS tile,
// then emit MFMA-fragment units (64 lanes x 16B each) + A2C-prescaled rounded
// row sumsq. No atomics: each block owns its 32 tokens' q2/k2 entries.
__global__ __launch_bounds__(256) void prep(
    const float* __restrict__ qkv, short8* __restrict__ qsw,
    short8* __restrict__ ksw, short8* __restrict__ vsw,
    float* __restrict__ q2, float* __restrict__ k2) {
  __shared__ unsigned short tile[32 * 584];   // row stride 584 (1168B, 16-mult)
  const int t = threadIdx.x;
  const int b = blockIdx.x >> 7;
  const int sc = blockIdx.x & 127;
  const float* src = qkv + ((size_t)(b * TT + sc * 32)) * (3 * CD);
#pragma unroll
  for (int j = 0; j < 18; ++j) {              // 4608 float4s / 256 thr
    int f = j * 256 + t;
    int row = f / 144, c4 = (f % 144) * 4;
    float4v x = *(const float4v*)(src + (size_t)row * 576 + c4);
    unsigned r0 = (unsigned)f2bf(x[0]) | ((unsigned)f2bf(x[1]) << 16);
    unsigned r1 = (unsigned)f2bf(x[2]) | ((unsigned)f2bf(x[3]) << 16);
    *(uint2v*)&tile[row * 584 + c4] = (uint2v){r0, r1};
  }
  __syncthreads();

  const int lane = t & 63, w = t >> 6;
  const int L = lane & 15, q = lane >> 4;
  // waves 0,1 -> q (s16o = w), waves 2,3 -> k (s16o = w-2)
  const int which = w >> 1;
  const int s16o = w & 1;
  const int row = s16o * 16 + L;
  short8* dst = which ? ksw : qsw;
  const size_t ubase = ((size_t)(b * 256 + sc * 2 + s16o)) * 6;
  float ss = 0.f;
#pragma unroll
  for (int ch = 0; ch < 6; ++ch) {
    short8 fr = *(const short8*)&tile[row * 584 + which * CD + ch * 32 + q * 8];
#pragma unroll
    for (int j = 0; j < 8; ++j) {
      float f = bf2f((unsigned short)fr[j]);
      ss += f * f;
    }
    dst[(ubase + ch) * 64 + lane] = fr;
  }
  ss += __shfl_xor(ss, 16);
  ss += __shfl_xor(ss, 32);                   // sum over 4 quads (192 ch)
  if (lane < 16)
    (which ? k2 : q2)[b * TT + sc * 32 + s16o * 16 + lane] = ss * A2C;

  // v fragments: 12 nt2-units, 3 per wave. lane(q,L): V[q*8+j][nt2*16+L]
#pragma unroll
  for (int i = 0; i < 3; ++i) {
    int nt2 = w * 3 + i;
    short8 fr;
#pragma unroll
    for (int j = 0; j < 8; ++j)
      fr[j] = (short)tile[(q * 8 + j) * 584 + 2 * CD + nt2 * 16 + L];
    vsw[((size_t)(b * 12 + nt2) * 128 + sc) * 64 + lane] = fr;
  }
}

// ---------------- main fused attention --------------------------------------
// grid 512 = 8 b x 64 q-tiles; block 256 = 4 waves x 16 q-rows.
// 128 s-iters of 32; K,V LDS double-buffered via global_load_lds width 16.
// 58368B LDS -> 2 blocks/CU (independent barriers overlap each other's drain).
__global__ __launch_bounds__(256, 2) void attn2(
    const short8* __restrict__ qsw, const short8* __restrict__ ksw,
    const short8* __restrict__ vsw, const float* __restrict__ q2,
    const float* __restrict__ k2, float* __restrict__ out) {
  // LDS: K dbuf 2x12KB | V dbuf 2x12KB | P scratch 4 waves x 16x36 fp32
  __shared__ __align__(16) unsigned char s_lds[49152 + 9216];
  float* ldsP = (float*)(s_lds + 49152);

  const int tid = threadIdx.x;
  const int w = tid >> 6;
  const int lane = tid & 63;
  const int L = lane & 15;
  const int q = lane >> 4;
  const int b = blockIdx.x & 7;      // batch -> XCD (and blk, blk+256 same CU
  const int qt = blockIdx.x >> 3;    //   share batch -> shared K/V in L2)
  const int q0 = qt * 64 + w * 16;   // this wave's 16 q-rows
  const size_t bT = (size_t)b * TT;

  float* pw = ldsP + w * 576;        // wave-private 16x36 P scratch

  // staging pointers (strength-reduced: += const stride per tile)
  const char* gka[3];
  const char* gva[3];
  char* lka[3];
  char* lva[3];
#pragma unroll
  for (int j = 0; j < 3; ++j) {
    int u = w * 3 + j;
    gka[j] = (const char*)ksw + ((size_t)(b * 256) * 6 * 64 + u * 64 + lane) * 16;
    gva[j] = (const char*)vsw + (((size_t)(b * 12 + u) * 128) * 64 + lane) * 16;
    lka[j] = (char*)s_lds + u * 1024;
    lva[j] = (char*)s_lds + 24576 + u * 1024;
  }
  // issue stage of current tile into buf, advance pointers to next tile
  auto stage = [&](int buf) {
#pragma unroll
    for (int j = 0; j < 3; ++j) {
      __builtin_amdgcn_global_load_lds(
          (const __attribute__((address_space(1))) void*)gka[j],
          (__attribute__((address_space(3))) void*)(lka[j] + buf * 12288), 16, 0, 0);
      gka[j] += 12288;             // 2 s16-units x 6 ch x 64 lanes x 16B
    }
#pragma unroll
    for (int j = 0; j < 3; ++j) {
      __builtin_amdgcn_global_load_lds(
          (const __attribute__((address_space(1))) void*)gva[j],
          (__attribute__((address_space(3))) void*)(lva[j] + buf * 12288), 16, 0, 0);
      gva[j] += 1024;              // 64 lanes x 16B per itile
    }
  };

  // Q fragments: unit ((b*256 + s16)*6 + ch), s16 = q0/16 = qt*4 + w
  short8 qf[6];
#pragma unroll
  for (int ch = 0; ch < 6; ++ch)
    qf[ch] = qsw[((size_t)(b * 256 + (q0 >> 4)) * 6 + ch) * 64 + lane];

  float q2l[4];
#pragma unroll
  for (int r = 0; r < 4; ++r) q2l[r] = q2[bT + q0 + 4 * q + r];

  float4v oacc[12];
#pragma unroll
  for (int nt = 0; nt < 12; ++nt) oacc[nt] = (float4v){0.f, 0.f, 0.f, 0.f};
  float lsum[4] = {0.f, 0.f, 0.f, 0.f};

  stage(0);
  // k2 for tile 0 (prefetched each iter thereafter)
  float k2l[2];
  k2l[0] = k2[bT + L];
  k2l[1] = k2[bT + 16 + L];
  __syncthreads();   // drains vmcnt -> tile0 ready

#pragma unroll 1
  for (int it = 0; it < 128; ++it) {
    const int cur = it & 1;
    if (it + 1 < 128) stage(cur ^ 1);   // overlap with compute

    // prefetch next tile's k2 (used next iter; hides scalar-load latency)
    float k2n[2];
    if (it + 1 < 128) {
      k2n[0] = k2[bT + (it + 1) * 32 + L];
      k2n[1] = k2[bT + (it + 1) * 32 + 16 + L];
    }

    // ---- S = Q.K^T from LDS K fragments ----
    float4v sacc[2];
    sacc[0] = (float4v){0.f, 0.f, 0.f, 0.f};
    sacc[1] = (float4v){0.f, 0.f, 0.f, 0.f};
#pragma unroll
    for (int ch = 0; ch < 6; ++ch) {
      short8 kf0 = *(const short8*)(s_lds + cur * 12288 + ch * 1024 + lane * 16);
      short8 kf1 = *(const short8*)(s_lds + cur * 12288 + (6 + ch) * 1024 + lane * 16);
      sacc[0] = __builtin_amdgcn_mfma_f32_16x16x32_bf16(qf[ch], kf0, sacc[0], 0, 0, 0);
      sacc[1] = __builtin_amdgcn_mfma_f32_16x16x32_bf16(qf[ch], kf1, sacc[1], 0, 0, 0);
    }

    // ---- V fragments from LDS (issue early; used after P) ----
    short8 vf[12];
#pragma unroll
    for (int nt = 0; nt < 12; ++nt)
      vf[nt] = *(const short8*)(s_lds + 24576 + cur * 12288 + nt * 1024 + lane * 16);

    // ---- P = exp(-dist); C-layout row=4q+r, col=nt*16+L -> LDS -> A-layout --
#pragma unroll
    for (int nt = 0; nt < 2; ++nt)
#pragma unroll
      for (int r = 0; r < 4; ++r) {
        float dot = sacc[nt][r];
        float tt = fmaf(-2.f * A2C, dot, q2l[r] + k2l[nt]);   // scaled d2
        float y = fmaxf(tt, 0.f);
        float p = __builtin_amdgcn_exp2f(-__builtin_amdgcn_sqrtf(y));
        lsum[r] += p;
        pw[(4 * q + r) * 36 + nt * 16 + L] = p;
      }
    float4v p0 = *(const float4v*)(pw + L * 36 + q * 8);
    float4v p1 = *(const float4v*)(pw + L * 36 + q * 8 + 4);
    // pack 8 fp32 -> 8 bf16 with 4 HW cvt_pk (RNE, replaces 24-VALU manual)
    uint4v pd;
    pd[0] = cvtpk_bf16(p0[0], p0[1]);
    pd[1] = cvtpk_bf16(p0[2], p0[3]);
    pd[2] = cvtpk_bf16(p1[0], p1[1]);
    pd[3] = cvtpk_bf16(p1[2], p1[3]);
    short8 paf = __builtin_bit_cast(short8, pd);

    // ---- O += P.V ----
#pragma unroll
    for (int nt = 0; nt < 12; ++nt)
      oacc[nt] = __builtin_amdgcn_mfma_f32_16x16x32_bf16(paf, vf[nt], oacc[nt], 0, 0, 0);

    k2l[0] = k2n[0];
    k2l[1] = k2n[1];
    __syncthreads();   // drain stage(it+1) + release buf[cur]
  }

  // ---- epilogue: normalize, write out (wave-private) ----
#pragma unroll
  for (int r = 0; r < 4; ++r) {
    float ls = lsum[r];
#pragma unroll
    for (int m = 1; m < 16; m <<= 1) ls += __shfl_xor(ls, m);
    float linv = 1.f / ls;
#pragma unroll
    for (int nt = 0; nt < 12; ++nt)
      out[(bT + q0 + 4 * q + r) * CD + nt * 16 + L] = oacc[nt][r] * linv;
  }
}

extern "C" void kernel_launch(void* const* d_in, const int* in_sizes, int n_in,
                              void* d_out, int out_size, void* d_ws, size_t ws_size,
                              hipStream_t stream) {
  (void)in_sizes; (void)n_in; (void)out_size; (void)ws_size;
  const float* qkv = (const float*)d_in[0];
  float* out = (float*)d_out;

  short8* qsw = (short8*)d_ws;                       // 8*256*6 units
  short8* ksw = qsw + (size_t)BB * 256 * 6 * 64;
  short8* vsw = ksw + (size_t)BB * 256 * 6 * 64;     // 8*12*128 units
  float* q2 = (float*)(vsw + (size_t)BB * 12 * 128 * 64);
  float* k2 = q2 + (size_t)BB * TT;

  prep<<<BB * 128, 256, 0, stream>>>(qkv, qsw, ksw, vsw, q2, k2);
  attn2<<<BB * 64, 256, 0, stream>>>(qsw, ksw, vsw, q2, k2, out);
}